// Round 5
// baseline (185.699 us; speedup 1.0000x reference)
//
#include <hip/hip_runtime.h>
#include <hip/hip_bf16.h>
#include <cstddef>
#include <cstdint>

#define B_ 2
#define S_ 2048
#define E_ 1024
#define H_ 16
#define D_ 64
#define WIN_ 3

using bf16x8 = __attribute__((ext_vector_type(8))) short;  // 8 bf16 = 4 VGPRs
using f32x4  = __attribute__((ext_vector_type(4))) float;  // MFMA C/D

static __device__ __forceinline__ unsigned short f2bf(float f) {
    union { float f; unsigned int u; } c; c.f = f;
    unsigned int r = c.u + 0x7FFF + ((c.u >> 16) & 1);   // round-to-nearest-even
    return (unsigned short)(r >> 16);
}

static __device__ __forceinline__ void gload16(const void* g, void* l) {
    __builtin_amdgcn_global_load_lds(
        (const __attribute__((address_space(1))) void*)g,
        (__attribute__((address_space(3))) void*)l, 16, 0, 0);
}

// XOR-swizzled LDS index (shorts) for [row][chunk-of-8-shorts] tiles with
// 64-short rows: slot = chunk ^ (row & 7). Breaks the 128B-row 16-way bank
// aliasing while staying global_load_lds-compatible (lane*16B contiguous).
#define SWZ(row, c) ((((row) * 8) + ((c) ^ ((row) & 7))) * 8)

// ---------------------------------------------------------------------------
// fp32 -> bf16 cast: y=0: x (4M elems), y=1..3: Wq/Wk/Wv (1M each)
// ---------------------------------------------------------------------------
__global__ __launch_bounds__(256) void cast_kernel(
    const float* __restrict__ X,  const float* __restrict__ Wq,
    const float* __restrict__ Wk, const float* __restrict__ Wv,
    unsigned short* __restrict__ xb,  unsigned short* __restrict__ wqb,
    unsigned short* __restrict__ wkb, unsigned short* __restrict__ wvb)
{
    const float* src; unsigned short* dst; int n;
    switch (blockIdx.y) {
        case 0:  src = X;  dst = xb;  n = B_ * S_ * E_; break;
        case 1:  src = Wq; dst = wqb; n = E_ * E_;      break;
        case 2:  src = Wk; dst = wkb; n = E_ * E_;      break;
        default: src = Wv; dst = wvb; n = E_ * E_;      break;
    }
    int i = (blockIdx.x * 256 + threadIdx.x) * 8;
    if (i >= n) return;
    float4 a = *(const float4*)(src + i);
    float4 b = *(const float4*)(src + i + 4);
    ushort4 lo, hi;
    lo.x = f2bf(a.x); lo.y = f2bf(a.y); lo.z = f2bf(a.z); lo.w = f2bf(a.w);
    hi.x = f2bf(b.x); hi.y = f2bf(b.y); hi.z = f2bf(b.z); hi.w = f2bf(b.w);
    *(ushort4*)(dst + i)     = lo;
    *(ushort4*)(dst + i + 4) = hi;
}

// ---------------------------------------------------------------------------
// bf16 MFMA projection GEMM (m97 structure + swizzled LDS):
// C[i,j] = sum_k A[i,k]*B[j,k]; 128x128 tile, BK=64, 4 waves, 4x4 frags.
// z=0: A=x, B=Wq -> q bf16 [B,H,S,D] scaled 1/8
// z=1: A=x, B=Wk -> k bf16 [B,H,S,D]
// z=2: A=Wv, B=x (swapped) -> v bf16 [B,H,D,S] with coalesced stores
// ---------------------------------------------------------------------------
__global__ __launch_bounds__(256, 3) void gemm_kernel(
    const unsigned short* __restrict__ xb,
    const unsigned short* __restrict__ wqb, const unsigned short* __restrict__ wkb,
    const unsigned short* __restrict__ wvb,
    const float* __restrict__ bq, const float* __restrict__ bk,
    const float* __restrict__ bv,
    unsigned short* __restrict__ qb, unsigned short* __restrict__ kb,
    unsigned short* __restrict__ vb)
{
    constexpr int BM = 128, BK = 64;
    __shared__ unsigned short As[BM * BK];   // 16 KB, swizzled rows of 64 shorts
    __shared__ unsigned short Bs[BM * BK];   // 16 KB

    const int t    = threadIdx.x;
    const int lane = t & 63;
    const int w    = t >> 6;
    const int l15  = lane & 15;
    const int quad = lane >> 4;
    const int wm   = w & 1;
    const int wn   = w >> 1;
    const int m0   = blockIdx.x * BM;
    const int n0   = blockIdx.y * BM;
    const int z    = blockIdx.z;

    const unsigned short *Ab, *Bb; const float* bias; unsigned short* outp;
    int i0, j0; float sc = 1.0f;
    if (z == 0)      { Ab = xb;  Bb = wqb; bias = bq; outp = qb; i0 = m0; j0 = n0; sc = 0.125f; }
    else if (z == 1) { Ab = xb;  Bb = wkb; bias = bk; outp = kb; i0 = m0; j0 = n0; }
    else             { Ab = wvb; Bb = xb;  bias = bv; outp = vb; i0 = n0; j0 = m0; }

    const int lrow = lane >> 3;                         // 0..7
    const int gch  = ((lane & 7) ^ (lrow & 7)) * 8;     // swizzle-inverse global chunk
    const int lsl  = (lane & 7) * 8;                    // physical LDS slot (shorts)

    f32x4 acc[4][4];
    #pragma unroll
    for (int mt = 0; mt < 4; ++mt)
        #pragma unroll
        for (int nt = 0; nt < 4; ++nt)
            #pragma unroll
            for (int r = 0; r < 4; ++r) acc[mt][nt][r] = 0.f;

    for (int k0 = 0; k0 < E_; k0 += BK) {
        __syncthreads();
        #pragma unroll
        for (int is = 0; is < 4; ++is) {
            int r = (w * 4 + is) * 8 + lrow;
            gload16(Ab + (size_t)(i0 + r) * E_ + k0 + gch, &As[r * BK + lsl]);
            gload16(Bb + (size_t)(j0 + r) * E_ + k0 + gch, &Bs[r * BK + lsl]);
        }
        __syncthreads();

        #pragma unroll
        for (int ks = 0; ks < 2; ++ks) {
            bf16x8 af[4], bfr[4];
            #pragma unroll
            for (int mt = 0; mt < 4; ++mt)
                af[mt] = *(const bf16x8*)&As[SWZ(wm*64 + mt*16 + l15, ks*4 + quad)];
            #pragma unroll
            for (int nt = 0; nt < 4; ++nt)
                bfr[nt] = *(const bf16x8*)&Bs[SWZ(wn*64 + nt*16 + l15, ks*4 + quad)];
            #pragma unroll
            for (int mt = 0; mt < 4; ++mt)
                #pragma unroll
                for (int nt = 0; nt < 4; ++nt)
                    acc[mt][nt] = __builtin_amdgcn_mfma_f32_16x16x32_bf16(
                        af[mt], bfr[nt], acc[mt][nt], 0, 0, 0);
        }
    }

    if (z < 2) {
        float bj[4];
        #pragma unroll
        for (int nt = 0; nt < 4; ++nt) bj[nt] = bias[j0 + wn*64 + nt*16 + l15];
        #pragma unroll
        for (int mt = 0; mt < 4; ++mt) {
            #pragma unroll
            for (int r = 0; r < 4; ++r) {
                int i = i0 + wm*64 + mt*16 + quad*4 + r;   // m index (b,s)
                int b = i >> 11, s = i & (S_ - 1);
                #pragma unroll
                for (int nt = 0; nt < 4; ++nt) {
                    int j = j0 + wn*64 + nt*16 + l15;      // n index (h,d)
                    int h = j >> 6, d = j & 63;
                    outp[(((size_t)(b * H_ + h) * S_) + s) * D_ + d] =
                        f2bf((acc[mt][nt][r] + bj[nt]) * sc);
                }
            }
        }
    } else {
        #pragma unroll
        for (int mt = 0; mt < 4; ++mt) {
            #pragma unroll
            for (int r = 0; r < 4; ++r) {
                int i = i0 + wm*64 + mt*16 + quad*4 + r;   // n index (h,d)
                int h = i >> 6, d = i & 63;
                float bi = bias[i];
                #pragma unroll
                for (int nt = 0; nt < 4; ++nt) {
                    int j = j0 + wn*64 + nt*16 + l15;      // m index (b,s)
                    int b = j >> 11, s = j & (S_ - 1);
                    outp[(((size_t)(b * H_ + h) * D_) + d) * S_ + s] =
                        f2bf(acc[mt][nt][r] + bi);
                }
            }
        }
    }
}

// ---------------------------------------------------------------------------
// MFMA attention. Block = 256 threads = 4 waves; 128 queries/block, 32/wave.
// K-tiles of 64. Computes S^T = K.Q^T (A=K frags, B=Q frags) so the C-layout
// holds 4 CONSECUTIVE KEYS per lane -> P lands in Pq[q][key] as packed
// ds_write_b64 (8/iter instead of 32 scalar b16). K/V frag reads amortize
// over 2 q-subtiles (mt). P rows wave-private: 2 barriers/iter only.
// Denominator accumulated from the SAME truncated p values so the bf16
// truncation bias cancels exactly under normalization; per-lane denom is a
// single scalar for q = wq0 + mt*16 + l15 (reduced via shfl_xor 16,32).
// ---------------------------------------------------------------------------
__global__ __launch_bounds__(256, 3) void attn_kernel(
    const unsigned short* __restrict__ Q, const unsigned short* __restrict__ K,
    const unsigned short* __restrict__ V, float* __restrict__ out)
{
    constexpr int TQ = 128, TK = 64, PSTR = 72;
    __shared__ unsigned short Ks[TK * 64];    // 8 KB, swizzled [key][d]
    __shared__ unsigned short Vt[D_ * 64];    // 8 KB, swizzled [d][key]
    __shared__ unsigned short Pq[TQ * PSTR];  // 18 KB, [q_loc][key] bf16, wave-private rows
    __shared__ float          Dsm[TQ];        // 512 B, denom exchange

    const int t    = threadIdx.x;
    const int lane = t & 63;
    const int w    = t >> 6;        // wave 0..3
    const int l15  = lane & 15;
    const int quad = lane >> 4;
    const int bh   = blockIdx.y;
    const int q0   = blockIdx.x * TQ;
    const int wq0  = q0 + w * 32;   // this wave's query base (32 rows)

    const unsigned short* Qp = Q + (size_t)bh * S_ * D_;
    const unsigned short* Kp = K + (size_t)bh * S_ * D_;
    const unsigned short* Vp = V + (size_t)bh * D_ * S_;   // [d][s]

    // Q B-operand frags held in regs for the whole kernel: [mt][ks]
    bf16x8 qf[2][2];
    #pragma unroll
    for (int mt = 0; mt < 2; ++mt)
        #pragma unroll
        for (int ks = 0; ks < 2; ++ks)
            qf[mt][ks] = *(const bf16x8*)(Qp + (size_t)(wq0 + mt*16 + l15) * D_
                                          + ks*32 + quad*8);

    f32x4 Oacc[2][4];
    #pragma unroll
    for (int mt = 0; mt < 2; ++mt)
        #pragma unroll
        for (int nt = 0; nt < 4; ++nt)
            #pragma unroll
            for (int r = 0; r < 4; ++r) Oacc[mt][nt][r] = 0.f;
    float dsum[2] = {};

    // staging: 256 threads stage Ks (64x64) + Vt (64x64), 2 gload16 each
    const int srow = t >> 3;                          // 0..31
    const int gch  = ((t & 7) ^ (srow & 7)) * 8;      // swizzle-inverse chunk (shorts)
    const unsigned short* kg0 = Kp + (size_t)srow * D_ + gch;          // rows 0..31
    const unsigned short* kg1 = Kp + (size_t)(srow + 32) * D_ + gch;   // rows 32..63
    const unsigned short* vg0 = Vp + (size_t)srow * S_ + gch;
    const unsigned short* vg1 = Vp + (size_t)(srow + 32) * S_ + gch;

    for (int k0 = 0; k0 < S_; k0 += TK) {
        __syncthreads();                 // prior iter done reading Ks/Vt
        gload16(kg0, &Ks[t * 8]);
        gload16(kg1, &Ks[2048 + t * 8]);
        gload16(vg0, &Vt[t * 8]);
        gload16(vg1, &Vt[2048 + t * 8]);
        kg0 += TK * D_; kg1 += TK * D_;
        vg0 += TK;      vg1 += TK;
        __syncthreads();                 // staged (compiler drains vmcnt)

        // ---- S^T = K Q^T : 64 keys (m) x 32 q (n) per wave ----
        f32x4 sacc[2][4];
        #pragma unroll
        for (int mt = 0; mt < 2; ++mt)
            #pragma unroll
            for (int nt = 0; nt < 4; ++nt)
                #pragma unroll
                for (int r = 0; r < 4; ++r) sacc[mt][nt][r] = 0.f;

        #pragma unroll
        for (int nt = 0; nt < 4; ++nt) {           // key tiles
            bf16x8 kf0 = *(const bf16x8*)&Ks[SWZ(nt*16 + l15, quad)];
            bf16x8 kf1 = *(const bf16x8*)&Ks[SWZ(nt*16 + l15, 4 + quad)];
            #pragma unroll
            for (int mt = 0; mt < 2; ++mt) {       // q tiles
                sacc[mt][nt] = __builtin_amdgcn_mfma_f32_16x16x32_bf16(
                    kf0, qf[mt][0], sacc[mt][nt], 0, 0, 0);
                sacc[mt][nt] = __builtin_amdgcn_mfma_f32_16x16x32_bf16(
                    kf1, qf[mt][1], sacc[mt][nt], 0, 0, 0);
            }
        }

        // ---- exp + (rare) inverted-window mask; packed b64 P writes ----
        #pragma unroll
        for (int mt = 0; mt < 2; ++mt) {
            const int qt0 = wq0 + mt*16;
            #pragma unroll
            for (int nt = 0; nt < 4; ++nt) {
                const int kt0 = k0 + nt*16;
                const bool band = (unsigned)(qt0 - kt0 + 18) <= 36u;  // wave-uniform
                union { unsigned short s[4]; unsigned long long u; } pk;
                #pragma unroll
                for (int r = 0; r < 4; ++r) {
                    float p;
                    if (band) {
                        int dlt = (qt0 + l15) - (kt0 + quad*4 + r);
                        if (dlt < 0) dlt = -dlt;
                        p = (dlt <= WIN_) ? 0.f : __expf(sacc[mt][nt][r]);
                    } else {
                        p = __expf(sacc[mt][nt][r]);
                    }
                    union { float f; unsigned int u; } c; c.f = p;
                    c.u &= 0xFFFF0000u;                  // bf16-representable
                    dsum[mt] += c.f;
                    pk.s[r] = (unsigned short)(c.u >> 16);
                }
                *(unsigned long long*)&Pq[(w*32 + mt*16 + l15) * PSTR
                                          + nt*16 + quad*4] = pk.u;
            }
        }
        // no barrier: P rows are wave-private

        // ---- O += P V : A = P rows (q-major), B = Vt rows (d-major) ----
        #pragma unroll
        for (int ks = 0; ks < 2; ++ks) {
            bf16x8 pf[2];
            #pragma unroll
            for (int mt = 0; mt < 2; ++mt)
                pf[mt] = *(const bf16x8*)&Pq[(w*32 + mt*16 + l15) * PSTR
                                             + ks*32 + quad*8];
            #pragma unroll
            for (int nt = 0; nt < 4; ++nt) {
                bf16x8 vf = *(const bf16x8*)&Vt[SWZ(nt*16 + l15, ks*4 + quad)];
                #pragma unroll
                for (int mt = 0; mt < 2; ++mt)
                    Oacc[mt][nt] = __builtin_amdgcn_mfma_f32_16x16x32_bf16(
                        pf[mt], vf, Oacc[mt][nt], 0, 0, 0);
            }
        }
    }

    // ---- denom reduce (quad dim) + exchange to C-layout via LDS ----
    #pragma unroll
    for (int mt = 0; mt < 2; ++mt) {
        float d = dsum[mt];
        d += __shfl_xor(d, 16);
        d += __shfl_xor(d, 32);
        Dsm[w*32 + mt*16 + l15] = d;     // all quads write same value (benign)
    }
    // wave-private region; in-order DS ops make the values visible

    const int b  = bh >> 4;
    const int hh = bh & 15;
    #pragma unroll
    for (int mt = 0; mt < 2; ++mt) {
        #pragma unroll
        for (int r = 0; r < 4; ++r) {
            const float iv = 1.f / Dsm[w*32 + mt*16 + quad*4 + r];
            const int qg = wq0 + mt*16 + quad*4 + r;
            float* op = out + (((size_t)b * S_ + qg) * H_ + hh) * D_;
            #pragma unroll
            for (int nt = 0; nt < 4; ++nt)
                op[nt*16 + l15] = Oacc[mt][nt][r] * iv;
        }
    }
}

extern "C" void kernel_launch(void* const* d_in, const int* in_sizes, int n_in,
                              void* d_out, int out_size, void* d_ws, size_t ws_size,
                              hipStream_t stream) {
    const float* x  = (const float*)d_in[0];
    const float* Wq = (const float*)d_in[1];
    const float* bq = (const float*)d_in[2];
    const float* Wk = (const float*)d_in[3];
    const float* bk = (const float*)d_in[4];
    const float* Wv = (const float*)d_in[5];
    const float* bv = (const float*)d_in[6];
    float* out = (float*)d_out;

    const size_t per = (size_t)B_ * H_ * S_ * D_;   // 4,194,304 elements
    const size_t wsz = (size_t)E_ * E_;             // 1,048,576
    unsigned short* qb  = (unsigned short*)d_ws;
    unsigned short* kb  = qb + per;
    unsigned short* vb  = kb + per;
    unsigned short* xbf = vb + per;
    unsigned short* wqb = xbf + per;
    unsigned short* wkb = wqb + wsz;
    unsigned short* wvb = wkb + wsz;

    dim3 cgrid((B_ * S_ * E_ + 2047) / 2048, 4);
    cast_kernel<<<cgrid, 256, 0, stream>>>(x, Wq, Wk, Wv, xbf, wqb, wkb, wvb);

    dim3 ggrid(B_ * S_ / 128, E_ / 128, 3);
    gemm_kernel<<<ggrid, 256, 0, stream>>>(xbf, wqb, wkb, wvb, bq, bk, bv, qb, kb, vb);

    dim3 agrid(S_ / 128, B_ * H_);
    attn_kernel<<<agrid, 256, 0, stream>>>(qb, kb, vb, out);
}

// Round 6
// 165.328 us; speedup vs baseline: 1.1232x; 1.1232x over previous
//
#include <hip/hip_runtime.h>
#include <hip/hip_bf16.h>
#include <cstddef>
#include <cstdint>

#define B_ 2
#define S_ 2048
#define E_ 1024
#define H_ 16
#define D_ 64
#define WIN_ 3

using bf16x8 = __attribute__((ext_vector_type(8))) short;  // 8 bf16 = 4 VGPRs
using f32x4  = __attribute__((ext_vector_type(4))) float;  // MFMA C/D

static __device__ __forceinline__ unsigned short f2bf(float f) {
    union { float f; unsigned int u; } c; c.f = f;
    unsigned int r = c.u + 0x7FFF + ((c.u >> 16) & 1);   // round-to-nearest-even
    return (unsigned short)(r >> 16);
}

static __device__ __forceinline__ void gload16(const void* g, void* l) {
    __builtin_amdgcn_global_load_lds(
        (const __attribute__((address_space(1))) void*)g,
        (__attribute__((address_space(3))) void*)l, 16, 0, 0);
}

// XOR-swizzled LDS index (shorts) for [row][chunk-of-8-shorts] tiles with
// 64-short rows: slot = chunk ^ (row & 7). Breaks the 128B-row 16-way bank
// aliasing while staying global_load_lds-compatible (lane*16B contiguous).
#define SWZ(row, c) ((((row) * 8) + ((c) ^ ((row) & 7))) * 8)

// ---------------------------------------------------------------------------
// fp32 -> bf16 cast: y=0: x (4M elems), y=1..3: Wq/Wk/Wv (1M each)
// ---------------------------------------------------------------------------
__global__ __launch_bounds__(256) void cast_kernel(
    const float* __restrict__ X,  const float* __restrict__ Wq,
    const float* __restrict__ Wk, const float* __restrict__ Wv,
    unsigned short* __restrict__ xb,  unsigned short* __restrict__ wqb,
    unsigned short* __restrict__ wkb, unsigned short* __restrict__ wvb)
{
    const float* src; unsigned short* dst; int n;
    switch (blockIdx.y) {
        case 0:  src = X;  dst = xb;  n = B_ * S_ * E_; break;
        case 1:  src = Wq; dst = wqb; n = E_ * E_;      break;
        case 2:  src = Wk; dst = wkb; n = E_ * E_;      break;
        default: src = Wv; dst = wvb; n = E_ * E_;      break;
    }
    int i = (blockIdx.x * 256 + threadIdx.x) * 8;
    if (i >= n) return;
    float4 a = *(const float4*)(src + i);
    float4 b = *(const float4*)(src + i + 4);
    ushort4 lo, hi;
    lo.x = f2bf(a.x); lo.y = f2bf(a.y); lo.z = f2bf(a.z); lo.w = f2bf(a.w);
    hi.x = f2bf(b.x); hi.y = f2bf(b.y); hi.z = f2bf(b.z); hi.w = f2bf(b.w);
    *(ushort4*)(dst + i)     = lo;
    *(ushort4*)(dst + i + 4) = hi;
}

// ---------------------------------------------------------------------------
// bf16 MFMA projection GEMM (m97 structure + swizzled LDS):
// C[i,j] = sum_k A[i,k]*B[j,k]; 128x128 tile, BK=64, 4 waves, 4x4 frags.
// launch_bounds(256,4): 4 blocks/CU for barrier-drain overlap (16 K-iters).
// z=0: A=x, B=Wq -> q bf16 [B,H,S,D] scaled 1/8
// z=1: A=x, B=Wk -> k bf16 [B,H,S,D]
// z=2: A=Wv, B=x (swapped) -> v bf16 [B,H,D,S] with coalesced stores
// ---------------------------------------------------------------------------
__global__ __launch_bounds__(256, 4) void gemm_kernel(
    const unsigned short* __restrict__ xb,
    const unsigned short* __restrict__ wqb, const unsigned short* __restrict__ wkb,
    const unsigned short* __restrict__ wvb,
    const float* __restrict__ bq, const float* __restrict__ bk,
    const float* __restrict__ bv,
    unsigned short* __restrict__ qb, unsigned short* __restrict__ kb,
    unsigned short* __restrict__ vb)
{
    constexpr int BM = 128, BK = 64;
    __shared__ unsigned short As[BM * BK];   // 16 KB, swizzled rows of 64 shorts
    __shared__ unsigned short Bs[BM * BK];   // 16 KB

    const int t    = threadIdx.x;
    const int lane = t & 63;
    const int w    = t >> 6;
    const int l15  = lane & 15;
    const int quad = lane >> 4;
    const int wm   = w & 1;
    const int wn   = w >> 1;
    const int m0   = blockIdx.x * BM;
    const int n0   = blockIdx.y * BM;
    const int z    = blockIdx.z;

    const unsigned short *Ab, *Bb; const float* bias; unsigned short* outp;
    int i0, j0; float sc = 1.0f;
    if (z == 0)      { Ab = xb;  Bb = wqb; bias = bq; outp = qb; i0 = m0; j0 = n0; sc = 0.125f; }
    else if (z == 1) { Ab = xb;  Bb = wkb; bias = bk; outp = kb; i0 = m0; j0 = n0; }
    else             { Ab = wvb; Bb = xb;  bias = bv; outp = vb; i0 = n0; j0 = m0; }

    const int lrow = lane >> 3;                         // 0..7
    const int gch  = ((lane & 7) ^ (lrow & 7)) * 8;     // swizzle-inverse global chunk
    const int lsl  = (lane & 7) * 8;                    // physical LDS slot (shorts)

    f32x4 acc[4][4];
    #pragma unroll
    for (int mt = 0; mt < 4; ++mt)
        #pragma unroll
        for (int nt = 0; nt < 4; ++nt)
            #pragma unroll
            for (int r = 0; r < 4; ++r) acc[mt][nt][r] = 0.f;

    for (int k0 = 0; k0 < E_; k0 += BK) {
        __syncthreads();
        #pragma unroll
        for (int is = 0; is < 4; ++is) {
            int r = (w * 4 + is) * 8 + lrow;
            gload16(Ab + (size_t)(i0 + r) * E_ + k0 + gch, &As[r * BK + lsl]);
            gload16(Bb + (size_t)(j0 + r) * E_ + k0 + gch, &Bs[r * BK + lsl]);
        }
        __syncthreads();

        #pragma unroll
        for (int ks = 0; ks < 2; ++ks) {
            bf16x8 af[4], bfr[4];
            #pragma unroll
            for (int mt = 0; mt < 4; ++mt)
                af[mt] = *(const bf16x8*)&As[SWZ(wm*64 + mt*16 + l15, ks*4 + quad)];
            #pragma unroll
            for (int nt = 0; nt < 4; ++nt)
                bfr[nt] = *(const bf16x8*)&Bs[SWZ(wn*64 + nt*16 + l15, ks*4 + quad)];
            #pragma unroll
            for (int mt = 0; mt < 4; ++mt)
                #pragma unroll
                for (int nt = 0; nt < 4; ++nt)
                    acc[mt][nt] = __builtin_amdgcn_mfma_f32_16x16x32_bf16(
                        af[mt], bfr[nt], acc[mt][nt], 0, 0, 0);
        }
    }

    if (z < 2) {
        float bj[4];
        #pragma unroll
        for (int nt = 0; nt < 4; ++nt) bj[nt] = bias[j0 + wn*64 + nt*16 + l15];
        #pragma unroll
        for (int mt = 0; mt < 4; ++mt) {
            #pragma unroll
            for (int r = 0; r < 4; ++r) {
                int i = i0 + wm*64 + mt*16 + quad*4 + r;   // m index (b,s)
                int b = i >> 11, s = i & (S_ - 1);
                #pragma unroll
                for (int nt = 0; nt < 4; ++nt) {
                    int j = j0 + wn*64 + nt*16 + l15;      // n index (h,d)
                    int h = j >> 6, d = j & 63;
                    outp[(((size_t)(b * H_ + h) * S_) + s) * D_ + d] =
                        f2bf((acc[mt][nt][r] + bj[nt]) * sc);
                }
            }
        }
    } else {
        #pragma unroll
        for (int mt = 0; mt < 4; ++mt) {
            #pragma unroll
            for (int r = 0; r < 4; ++r) {
                int i = i0 + wm*64 + mt*16 + quad*4 + r;   // n index (h,d)
                int h = i >> 6, d = i & 63;
                float bi = bias[i];
                #pragma unroll
                for (int nt = 0; nt < 4; ++nt) {
                    int j = j0 + wn*64 + nt*16 + l15;      // m index (b,s)
                    int b = j >> 11, s = j & (S_ - 1);
                    outp[(((size_t)(b * H_ + h) * D_) + d) * S_ + s] =
                        f2bf(acc[mt][nt][r] + bi);
                }
            }
        }
    }
}

// ---------------------------------------------------------------------------
// MFMA attention. Block = 512 threads = 8 waves; 128 queries/block, 16/wave
// (R3 skeleton: 16 waves/CU). K-tiles of 64. S^T = K.Q^T scoring so the
// C-layout holds 4 CONSECUTIVE KEYS per lane: P writes are 4 packed
// ds_write_b64/iter into a PSTR=64 + chunk-XOR-swizzled buffer (verified
// conflict-free for both b64 writes and b128 A-frag reads); denominator is
// one scalar/lane (q = l15). P rows wave-private: 2 barriers/iter.
// 1D grid with XCD swizzle: bh = (j&7)*4 + (j>>7) so each XCD's blocks
// share 4 bh (2MB K/V fits its private 4MB L2).
// Denominator accumulated from the SAME truncated p values so the bf16
// truncation bias cancels exactly under normalization.
// ---------------------------------------------------------------------------
__global__ __launch_bounds__(512, 4) void attn_kernel(
    const unsigned short* __restrict__ Q, const unsigned short* __restrict__ K,
    const unsigned short* __restrict__ V, float* __restrict__ out)
{
    constexpr int TQ = 128, TK = 64;
    __shared__ unsigned short Ks[TK * 64];   // 8 KB, swizzled [key][d]
    __shared__ unsigned short Vt[D_ * 64];   // 8 KB, swizzled [d][key]
    __shared__ unsigned short Pq[TQ * 64];   // 16 KB, [q_loc][key] bf16, chunk-swizzled

    const int t    = threadIdx.x;
    const int lane = t & 63;
    const int w    = t >> 6;        // wave 0..7
    const int l15  = lane & 15;
    const int quad = lane >> 4;

    // XCD-aware block swizzle (perf heuristic only)
    const int j    = blockIdx.x;
    const int bh   = (j & 7) * 4 + (j >> 7);
    const int q0   = ((j >> 3) & 15) * TQ;
    const int wq0  = q0 + w * 16;   // this wave's query base

    const unsigned short* Qp = Q + (size_t)bh * S_ * D_;
    const unsigned short* Kp = K + (size_t)bh * S_ * D_;
    const unsigned short* Vp = V + (size_t)bh * D_ * S_;   // [d][s]

    // Q B-operand frags held in regs for the whole kernel (n = q = l15)
    bf16x8 qf[2];
    #pragma unroll
    for (int ks = 0; ks < 2; ++ks)
        qf[ks] = *(const bf16x8*)(Qp + (size_t)(wq0 + l15) * D_ + ks*32 + quad*8);

    f32x4 Oacc[4];
    #pragma unroll
    for (int nt = 0; nt < 4; ++nt)
        #pragma unroll
        for (int r = 0; r < 4; ++r) Oacc[nt][r] = 0.f;
    float dsum = 0.f;               // denom for q = wq0 + l15

    // staging addresses (swizzle-inverse on the global side)
    const int lrow = lane >> 3;                       // 0..7
    const int gch  = ((lane & 7) ^ (lrow & 7)) * 8;   // shorts
    const int srow = w * 8 + lrow;                    // 0..63 (key row / d row)
    const unsigned short* kgp = Kp + (size_t)srow * D_ + gch;
    const unsigned short* vgp = Vp + (size_t)srow * S_ + gch;

    const int swzkey = (l15 & 7) << 1;  // per-q-row chunk XOR key for Pq

    for (int k0 = 0; k0 < S_; k0 += TK) {
        __syncthreads();                 // prior iter done reading Ks/Vt
        gload16(kgp, &Ks[t * 8]);
        gload16(vgp, &Vt[t * 8]);
        kgp += TK * D_;
        vgp += TK;
        __syncthreads();                 // staged (compiler drains vmcnt)

        // ---- S^T = K Q^T : 64 keys (m, 4 mt tiles) x 16 q (n) per wave ----
        f32x4 sacc[4];
        #pragma unroll
        for (int mt = 0; mt < 4; ++mt)
            #pragma unroll
            for (int r = 0; r < 4; ++r) sacc[mt][r] = 0.f;
        #pragma unroll
        for (int mt = 0; mt < 4; ++mt) {
            bf16x8 kf0 = *(const bf16x8*)&Ks[SWZ(mt*16 + l15, quad)];
            bf16x8 kf1 = *(const bf16x8*)&Ks[SWZ(mt*16 + l15, 4 + quad)];
            sacc[mt] = __builtin_amdgcn_mfma_f32_16x16x32_bf16(kf0, qf[0], sacc[mt], 0, 0, 0);
            sacc[mt] = __builtin_amdgcn_mfma_f32_16x16x32_bf16(kf1, qf[1], sacc[mt], 0, 0, 0);
        }

        // ---- exp + (rare) inverted-window mask; packed b64 P writes ----
        #pragma unroll
        for (int mt = 0; mt < 4; ++mt) {
            const int kt0 = k0 + mt*16;
            const bool band = (unsigned)(wq0 - kt0 + 18) <= 36u;  // wave-uniform
            union { unsigned short s[4]; unsigned long long u; } pk;
            #pragma unroll
            for (int r = 0; r < 4; ++r) {
                float p;
                if (band) {
                    int dlt = (wq0 + l15) - (kt0 + quad*4 + r);
                    if (dlt < 0) dlt = -dlt;
                    p = (dlt <= WIN_) ? 0.f : __expf(sacc[mt][r]);
                } else {
                    p = __expf(sacc[mt][r]);
                }
                union { float f; unsigned int u; } c; c.f = p;
                c.u &= 0xFFFF0000u;                  // bf16-representable
                dsum += c.f;
                pk.s[r] = (unsigned short)(c.u >> 16);
            }
            const int slot = (mt*4 + quad) ^ swzkey;     // conflict-free swizzle
            *(unsigned long long*)&Pq[(w*16 + l15) * 64 + slot * 4] = pk.u;
        }
        // no barrier: P rows are wave-private

        // ---- O += P V : A = P rows (m = q = l15), B = Vt rows (n = d) ----
        #pragma unroll
        for (int ks = 0; ks < 2; ++ks) {
            const int phys = (ks*8 + quad*2) ^ swzkey;   // even -> 16B aligned
            bf16x8 pf = *(const bf16x8*)&Pq[(w*16 + l15) * 64 + phys * 4];
            #pragma unroll
            for (int nt = 0; nt < 4; ++nt) {
                bf16x8 vf = *(const bf16x8*)&Vt[SWZ(nt*16 + l15, ks*4 + quad)];
                Oacc[nt] = __builtin_amdgcn_mfma_f32_16x16x32_bf16(pf, vf, Oacc[nt], 0, 0, 0);
            }
        }
    }

    // ---- denom: reduce across quads (q = l15), fetch via shuffle ----
    dsum += __shfl_xor(dsum, 16);
    dsum += __shfl_xor(dsum, 32);

    const int b  = bh >> 4;
    const int hh = bh & 15;
    #pragma unroll
    for (int r = 0; r < 4; ++r) {
        const float iv = 1.f / __shfl(dsum, quad*4 + r);   // denom(q = quad*4+r)
        const int qg = wq0 + quad*4 + r;
        float* op = out + (((size_t)b * S_ + qg) * H_ + hh) * D_;
        #pragma unroll
        for (int nt = 0; nt < 4; ++nt)
            op[nt*16 + l15] = Oacc[nt][r] * iv;
    }
}

extern "C" void kernel_launch(void* const* d_in, const int* in_sizes, int n_in,
                              void* d_out, int out_size, void* d_ws, size_t ws_size,
                              hipStream_t stream) {
    const float* x  = (const float*)d_in[0];
    const float* Wq = (const float*)d_in[1];
    const float* bq = (const float*)d_in[2];
    const float* Wk = (const float*)d_in[3];
    const float* bk = (const float*)d_in[4];
    const float* Wv = (const float*)d_in[5];
    const float* bv = (const float*)d_in[6];
    float* out = (float*)d_out;

    const size_t per = (size_t)B_ * H_ * S_ * D_;   // 4,194,304 elements
    const size_t wsz = (size_t)E_ * E_;             // 1,048,576
    unsigned short* qb  = (unsigned short*)d_ws;
    unsigned short* kb  = qb + per;
    unsigned short* vb  = kb + per;
    unsigned short* xbf = vb + per;
    unsigned short* wqb = xbf + per;
    unsigned short* wkb = wqb + wsz;
    unsigned short* wvb = wkb + wsz;

    dim3 cgrid((B_ * S_ * E_ + 2047) / 2048, 4);
    cast_kernel<<<cgrid, 256, 0, stream>>>(x, Wq, Wk, Wv, xbf, wqb, wkb, wvb);

    dim3 ggrid(B_ * S_ / 128, E_ / 128, 3);
    gemm_kernel<<<ggrid, 256, 0, stream>>>(xbf, wqb, wkb, wvb, bq, bk, bv, qb, kb, vb);

    attn_kernel<<<dim3(512), 512, 0, stream>>>(qb, kb, vb, out);
}